// Round 5
// baseline (413.811 us; speedup 1.0000x reference)
//
#include <hip/hip_runtime.h>

#define D 64
#define HOUR_PERIOD 6

// ---------- dtype helpers ----------
__device__ __forceinline__ float bf2f(unsigned short u) {
    union { unsigned int i; float f; } v; v.i = ((unsigned int)u) << 16; return v.f;
}
__device__ __forceinline__ unsigned short f2bf(float f) {
    union { float fl; unsigned int i; } v; v.fl = f;
    unsigned int x = v.i;
    return (unsigned short)((x + 0x7fffu + ((x >> 16) & 1u)) >> 16);
}
__device__ __forceinline__ float4 ld4(const void* base, int idx4, int fp32) {
    if (fp32) return reinterpret_cast<const float4*>(base)[idx4];
    ushort4 u = reinterpret_cast<const ushort4*>(base)[idx4];
    return make_float4(bf2f(u.x), bf2f(u.y), bf2f(u.z), bf2f(u.w));
}
__device__ __forceinline__ float ld1(const void* base, int i, int fp32) {
    return fp32 ? reinterpret_cast<const float*>(base)[i]
                : bf2f(reinterpret_cast<const unsigned short*>(base)[i]);
}

// ---------- DPP 16-lane row reduction (VALU pipe, no LDS/DS traffic) ----------
// row_ror:N ctrl = 0x120+N; rotations by 8,4,2,1 give every lane the row sum.
template <int CTRL>
__device__ __forceinline__ float dpp_add(float v) {
    union { float f; int i; } a, b;
    a.f = v;
    b.i = __builtin_amdgcn_update_dpp(0, a.i, CTRL, 0xF, 0xF, true);
    return v + b.f;
}
__device__ __forceinline__ float qsum(float v) {
    v = dpp_add<0x128>(v);   // ror 8
    v = dpp_add<0x124>(v);   // ror 4
    v = dpp_add<0x122>(v);   // ror 2
    v = dpp_add<0x121>(v);   // ror 1
    return v;
}
__device__ __forceinline__ float wsum64(float v) { // 64-lane butterfly (setup only)
    #pragma unroll
    for (int off = 32; off; off >>= 1) v += __shfl_xor(v, off, 64);
    return v;
}

// ---------- prep: zero cnt + dtype detect + trel table ----------
__global__ void k_prep(const void* __restrict__ hour_emb, const void* __restrict__ W,
                       const void* __restrict__ bias, const void* __restrict__ rel_emb,
                       int* __restrict__ flag, float* __restrict__ trel,
                       int* __restrict__ cnt, int M) {
    int b = blockIdx.x, t = threadIdx.x;
    int i4 = (b * 256 + t) * 4;
    if (i4 + 3 < M) {
        reinterpret_cast<int4*>(cnt)[b * 256 + t] = make_int4(0, 0, 0, 0);
    } else {
        for (int k = i4; k < M; ++k) cnt[k] = 0;
    }
    if (b < HOUR_PERIOD) {
        __shared__ float mix[D];
        int f = 0;
        if (t < 64) {
            // dtype detect: rel_emb rows are L2-normalized -> |v|<=1 if truly bf16
            float da = bf2f(reinterpret_cast<const unsigned short*>(rel_emb)[t]);
            float db = bf2f(reinterpret_cast<const unsigned short*>(rel_emb)[t + 64]);
            int bad = (!(fabsf(da) <= 100.f)) || (!(fabsf(db) <= 100.f));
            unsigned long long m = __ballot(bad);
            f = (m != 0ull) ? 1 : 0;
            if (b == 0 && t == 0) *flag = f;
            int last = (b - 1 + HOUR_PERIOD) % HOUR_PERIOD;
            int next = (b + 1) % HOUR_PERIOD;
            mix[t] = (ld1(hour_emb, last * D + t, f) + ld1(hour_emb, b * D + t, f) +
                      ld1(hour_emb, next * D + t, f)) * (1.f / 3.f);
        }
        __syncthreads();
        if (t < 64) {
            float y = ld1(bias, t, f);
            #pragma unroll
            for (int k = 0; k < D; ++k) y += mix[k] * ld1(W, t * D + k, f);
            float ss = wsum64(y * y);
            trel[b * D + t] = y / fmaxf(sqrtf(ss), 1e-12f);
        }
    }
}

// ---------- unified histogram over main (dst) + cat (N + cdst) ----------
__global__ void k_hist(const int* __restrict__ dst, const int* __restrict__ cdst,
                       int* __restrict__ cnt, int E, int EC, int N) {
    int i = blockIdx.x * blockDim.x + threadIdx.x;
    if (i >= E + EC) return;
    int d = (i < E) ? dst[i] : (N + cdst[i - E]);
    atomicAdd(&cnt[d], 1);
}

// ---------- single-block exclusive scan: cnt[0..n) -> row[0..n) ----------
__global__ void k_scan1(const int* __restrict__ cnt, int* __restrict__ row, int n) {
    __shared__ int wsum[16];
    int t = threadIdx.x;                 // 0..1023
    int CH = (n + 1023) >> 10;
    int base = t * CH;
    int lim = min(base + CH, n);
    int s = 0;
    for (int i = base; i < lim; ++i) s += cnt[i];
    int lane = t & 63, wv = t >> 6;
    int x = s;
    #pragma unroll
    for (int off = 1; off < 64; off <<= 1) {
        int y = __shfl_up(x, off, 64);
        if (lane >= off) x += y;
    }
    if (lane == 63) wsum[wv] = x;
    __syncthreads();
    if (wv == 0) {
        int v = (lane < 16) ? wsum[lane] : 0;
        #pragma unroll
        for (int off = 1; off < 16; off <<= 1) {
            int y = __shfl_up(v, off, 64);
            if (lane >= off) v += y;
        }
        if (lane < 16) wsum[lane] = v;
    }
    __syncthreads();
    int run = ((wv > 0) ? wsum[wv - 1] : 0) + (x - s);   // exclusive prefix
    for (int i = base; i < lim; ++i) { row[i] = run; run += cnt[i]; }
}

// ---------- unified scatter; bumps row[d] in place ----------
// main: src(17b) | ftype(3b)<<17 | hour(3b)<<20 ; cat: csrc plain
__global__ void k_scatter(const int* __restrict__ src, const int* __restrict__ dst,
                          const int* __restrict__ ft, const int* __restrict__ hh,
                          const int* __restrict__ csrc, const int* __restrict__ cdst,
                          int* __restrict__ row, unsigned* __restrict__ recs,
                          int E, int EC, int N) {
    int i = blockIdx.x * blockDim.x + threadIdx.x;
    if (i >= E + EC) return;
    int d; unsigned pk;
    if (i < E) {
        d = dst[i];
        pk = (unsigned)src[i] | ((unsigned)ft[i] << 17) | ((unsigned)hh[i] << 20);
    } else {
        int j = i - E;
        d = N + cdst[j];
        pk = (unsigned)csrc[j];
    }
    int p = atomicAdd(&row[d], 1);
    recs[p] = pk;
}

// ---------- fused aggregation for BOTH graphs ----------
// After scatter, row[d] = segment END; start = row[d] - cnt[d].
// d < N: TransH*time score; d >= N: TransE cat score. Softmax denom factors out:
// out[d] = sum_e es_e * h_e / sum_e es_e.
__launch_bounds__(256)
__global__ void k_fused(const void* __restrict__ nfeat, const void* __restrict__ cemb,
                        const void* __restrict__ rel_emb, const void* __restrict__ norm_emb,
                        const float* __restrict__ trel,
                        const int* __restrict__ row, const int* __restrict__ cnt,
                        const unsigned* __restrict__ recs,
                        const int* __restrict__ flag, void* __restrict__ out,
                        int N, int M) {
    int f = *flag;
    __shared__ float srel[7 * D], snorm[7 * D], strel[HOUR_PERIOD * D];
    int tid = threadIdx.x;
    for (int i = tid; i < 7 * D; i += 256) srel[i] = ld1(rel_emb, i, f);
    for (int i = tid; i < 7 * D; i += 256) snorm[i] = ld1(norm_emb, i, f);
    for (int i = tid; i < HOUR_PERIOD * D; i += 256) strel[i] = trel[i];
    __syncthreads();
    int l = tid & 15;
    int d = blockIdx.x * 16 + (tid >> 4);
    if (d >= M) return;
    int i1 = row[d];
    int i0 = i1 - cnt[d];
    float a0 = 0.f, a1 = 0.f, a2 = 0.f, a3 = 0.f, se = 0.f;

    if (d < N) {
        // ---- main graph (TransH on relation + time hyperplanes) ----
        float4 tt = ld4(nfeat, d * 16 + l, f);
        float4 qv = *reinterpret_cast<float4*>(&snorm[5 * D + l * 4]);   // time_norm
        unsigned pkA = 0, pkB = 0;
        float4 hA = make_float4(0,0,0,0), hB = hA;
        if (i0 < i1)     { pkA = recs[i0];     hA = ld4(nfeat, (int)(pkA & 0x1FFFF) * 16 + l, f); }
        if (i0 + 1 < i1) { pkB = recs[i0 + 1]; hB = ld4(nfeat, (int)(pkB & 0x1FFFF) * 16 + l, f); }
        for (int i = i0; i < i1; ++i) {
            unsigned cpk = pkA; float4 ch = hA;
            pkA = pkB; hA = hB;
            if (i + 2 < i1) { pkB = recs[i + 2]; hB = ld4(nfeat, (int)(pkB & 0x1FFFF) * 16 + l, f); }
            int ft = (cpk >> 17) & 7, hh = (cpk >> 20) & 7;
            float4 nn4 = *reinterpret_cast<float4*>(&snorm[ft * D + l * 4]);
            float4 rr4 = *reinterpret_cast<float4*>(&srel[ft * D + l * 4]);
            float4 tr4 = *reinterpret_cast<float4*>(&strel[hh * D + l * 4]);
            float w0 = ch.x - tt.x, w1 = ch.y - tt.y, w2 = ch.z - tt.z, w3 = ch.w - tt.w;
            float al = qsum(w0*nn4.x + w1*nn4.y + w2*nn4.z + w3*nn4.w);  // (h-t).n
            float be = qsum(w0*qv.x + w1*qv.y + w2*qv.z + w3*qv.w);      // (h-t).q
            float u0 = w0 + rr4.x - al*nn4.x, u1 = w1 + rr4.y - al*nn4.y,
                  u2 = w2 + rr4.z - al*nn4.z, u3 = w3 + rr4.w - al*nn4.w;
            float v0 = w0 + tr4.x - be*qv.x, v1 = w1 + tr4.y - be*qv.y,
                  v2 = w2 + tr4.z - be*qv.z, v3 = w3 + tr4.w - be*qv.w;
            float ssq = qsum(u0*u0 + u1*u1 + u2*u2 + u3*u3 +
                             v0*v0 + v1*v1 + v2*v2 + v3*v3);
            float es = __expf(__expf(-ssq));   // exp(score*score_t), arg in (0,1]
            a0 += es * ch.x; a1 += es * ch.y; a2 += es * ch.z; a3 += es * ch.w;
            se += es;
        }
    } else {
        // ---- category graph (TransE) ----
        float4 tt = ld4(cemb, (d - N) * 16 + l, f);
        float4 r6 = *reinterpret_cast<float4*>(&srel[6 * D + l * 4]);
        float b0 = r6.x - tt.x, b1 = r6.y - tt.y, b2 = r6.z - tt.z, b3 = r6.w - tt.w;
        unsigned pkA = 0, pkB = 0;
        float4 hA = make_float4(0,0,0,0), hB = hA;
        if (i0 < i1)     { pkA = recs[i0];     hA = ld4(cemb, (int)pkA * 16 + l, f); }
        if (i0 + 1 < i1) { pkB = recs[i0 + 1]; hB = ld4(cemb, (int)pkB * 16 + l, f); }
        for (int i = i0; i < i1; ++i) {
            float4 ch = hA;
            pkA = pkB; hA = hB;
            if (i + 2 < i1) { pkB = recs[i + 2]; hB = ld4(cemb, (int)pkB * 16 + l, f); }
            float d0 = ch.x + b0, d1 = ch.y + b1, d2 = ch.z + b2, d3 = ch.w + b3;
            float ssq = qsum(d0*d0 + d1*d1 + d2*d2 + d3*d3);
            float es = __expf(__expf(-ssq));
            a0 += es * ch.x; a1 += es * ch.y; a2 += es * ch.z; a3 += es * ch.w;
            se += es;
        }
    }
    float inv = (se > 0.f) ? 1.f / se : 0.f;   // zero-degree row -> zeros
    int oi = d * 16 + l;
    if (f) {
        reinterpret_cast<float4*>(out)[oi] = make_float4(a0*inv, a1*inv, a2*inv, a3*inv);
    } else {
        ushort4 o;
        o.x = f2bf(a0*inv); o.y = f2bf(a1*inv); o.z = f2bf(a2*inv); o.w = f2bf(a3*inv);
        reinterpret_cast<ushort4*>(out)[oi] = o;
    }
}

extern "C" void kernel_launch(void* const* d_in, const int* in_sizes, int n_in,
                              void* d_out, int out_size, void* d_ws, size_t ws_size,
                              hipStream_t stream) {
    const void* nfeat    = d_in[0];
    const void* cemb     = d_in[1];
    const void* rel_emb  = d_in[2];
    const void* norm_emb = d_in[3];
    const void* hour_emb = d_in[4];
    const void* trw      = d_in[5];
    const void* trb      = d_in[6];
    const int* src    = (const int*)d_in[7];
    const int* dst    = (const int*)d_in[8];
    const int* ftype  = (const int*)d_in[9];
    const int* hourid = (const int*)d_in[10];
    const int* csrc   = (const int*)d_in[11];
    const int* cdst   = (const int*)d_in[12];

    const int N  = in_sizes[0] / D;
    const int NC = in_sizes[1] / D;
    const int E  = in_sizes[7];
    const int EC = in_sizes[11];
    const int M  = N + NC;          // unified dst space
    const int ET = E + EC;          // unified edge count

    // ---- ws layout (4B units): flag(16) trel(384) cnt(M) row(M) recs(ET) ~ 4.1 MB ----
    int* ws     = (int*)d_ws;
    int* flag   = ws;
    float* trel = (float*)(ws + 16);
    int* cnt    = ws + 16 + HOUR_PERIOD * D;
    int* row    = cnt + M;
    unsigned* recs = (unsigned*)(row + M);

    int prepBlocks = ((M + 3) / 4 + 255) / 256;   // >= HOUR_PERIOD
    k_prep<<<prepBlocks, 256, 0, stream>>>(hour_emb, trw, trb, rel_emb,
                                           flag, trel, cnt, M);
    k_hist<<<(ET + 255) / 256, 256, 0, stream>>>(dst, cdst, cnt, E, EC, N);
    k_scan1<<<1, 1024, 0, stream>>>(cnt, row, M);
    k_scatter<<<(ET + 255) / 256, 256, 0, stream>>>(src, dst, ftype, hourid,
                                                    csrc, cdst, row, recs, E, EC, N);
    k_fused<<<(M + 15) / 16, 256, 0, stream>>>(nfeat, cemb, rel_emb, norm_emb,
                                               trel, row, cnt, recs, flag,
                                               d_out, N, M);
}

// Round 6
// 266.111 us; speedup vs baseline: 1.5550x; 1.5550x over previous
//
#include <hip/hip_runtime.h>

#define D 64
#define HOUR_PERIOD 6

// ---------- dtype helpers ----------
__device__ __forceinline__ float bf2f(unsigned short u) {
    union { unsigned int i; float f; } v; v.i = ((unsigned int)u) << 16; return v.f;
}
__device__ __forceinline__ unsigned short f2bf(float f) {
    union { float fl; unsigned int i; } v; v.fl = f;
    unsigned int x = v.i;
    return (unsigned short)((x + 0x7fffu + ((x >> 16) & 1u)) >> 16);
}
__device__ __forceinline__ float4 ld4(const void* base, int idx4, int fp32) {
    if (fp32) return reinterpret_cast<const float4*>(base)[idx4];
    ushort4 u = reinterpret_cast<const ushort4*>(base)[idx4];
    return make_float4(bf2f(u.x), bf2f(u.y), bf2f(u.z), bf2f(u.w));
}
__device__ __forceinline__ float ld1(const void* base, int i, int fp32) {
    return fp32 ? reinterpret_cast<const float*>(base)[i]
                : bf2f(reinterpret_cast<const unsigned short*>(base)[i]);
}

// ---------- DPP 16-lane row reduction (VALU pipe, no DS traffic) ----------
template <int CTRL>
__device__ __forceinline__ float dpp_add(float v) {
    union { float f; int i; } a, b;
    a.f = v;
    b.i = __builtin_amdgcn_update_dpp(0, a.i, CTRL, 0xF, 0xF, true);
    return v + b.f;
}
__device__ __forceinline__ float qsum(float v) {
    v = dpp_add<0x128>(v);   // row_ror:8
    v = dpp_add<0x124>(v);   // row_ror:4
    v = dpp_add<0x122>(v);   // row_ror:2
    v = dpp_add<0x121>(v);   // row_ror:1
    return v;
}
__device__ __forceinline__ float wsum64(float v) { // 64-lane butterfly (setup only)
    #pragma unroll
    for (int off = 32; off; off >>= 1) v += __shfl_xor(v, off, 64);
    return v;
}
__device__ __forceinline__ int wredi(int v) {      // 64-lane int reduce
    #pragma unroll
    for (int off = 32; off; off >>= 1) v += __shfl_xor(v, off, 64);
    return v;
}

// ---------- prep: zero cnt + dtype detect + trel table ----------
__global__ void k_prep(const void* __restrict__ hour_emb, const void* __restrict__ W,
                       const void* __restrict__ bias, const void* __restrict__ rel_emb,
                       int* __restrict__ flag, float* __restrict__ trel,
                       int* __restrict__ cnt, int M) {
    int b = blockIdx.x, t = threadIdx.x;
    int i4 = (b * 256 + t) * 4;
    if (i4 + 3 < M) {
        reinterpret_cast<int4*>(cnt)[b * 256 + t] = make_int4(0, 0, 0, 0);
    } else {
        for (int k = i4; k < M; ++k) cnt[k] = 0;
    }
    if (b < HOUR_PERIOD) {
        __shared__ float mix[D];
        int f = 0;
        if (t < 64) {
            // dtype detect: rel_emb rows are L2-normalized -> |v|<=1 if truly bf16
            float da = bf2f(reinterpret_cast<const unsigned short*>(rel_emb)[t]);
            float db = bf2f(reinterpret_cast<const unsigned short*>(rel_emb)[t + 64]);
            int bad = (!(fabsf(da) <= 100.f)) || (!(fabsf(db) <= 100.f));
            unsigned long long m = __ballot(bad);
            f = (m != 0ull) ? 1 : 0;
            if (b == 0 && t == 0) *flag = f;
            int last = (b - 1 + HOUR_PERIOD) % HOUR_PERIOD;
            int next = (b + 1) % HOUR_PERIOD;
            mix[t] = (ld1(hour_emb, last * D + t, f) + ld1(hour_emb, b * D + t, f) +
                      ld1(hour_emb, next * D + t, f)) * (1.f / 3.f);
        }
        __syncthreads();
        if (t < 64) {
            float y = ld1(bias, t, f);
            #pragma unroll
            for (int k = 0; k < D; ++k) y += mix[k] * ld1(W, t * D + k, f);
            float ss = wsum64(y * y);
            trel[b * D + t] = y / fmaxf(sqrtf(ss), 1e-12f);
        }
    }
}

// ---------- unified histogram, 4 edges/thread vectorized ----------
__global__ void k_hist(const int* __restrict__ dst, const int* __restrict__ cdst,
                       int* __restrict__ cnt, int E, int EC, int N) {
    int tid = blockIdx.x * blockDim.x + threadIdx.x;
    int mainT = (E + 3) / 4;
    if (tid < mainT) {
        int i = tid * 4;
        if (i + 3 < E) {
            int4 d = reinterpret_cast<const int4*>(dst)[tid];
            atomicAdd(&cnt[d.x], 1); atomicAdd(&cnt[d.y], 1);
            atomicAdd(&cnt[d.z], 1); atomicAdd(&cnt[d.w], 1);
        } else {
            for (int k = i; k < E; ++k) atomicAdd(&cnt[dst[k]], 1);
        }
    } else {
        int j = (tid - mainT) * 4;
        if (j + 3 < EC) {
            int4 d = reinterpret_cast<const int4*>(cdst)[tid - mainT];
            atomicAdd(&cnt[N + d.x], 1); atomicAdd(&cnt[N + d.y], 1);
            atomicAdd(&cnt[N + d.z], 1); atomicAdd(&cnt[N + d.w], 1);
        } else {
            for (int k = j; k < EC; ++k) atomicAdd(&cnt[N + cdst[k]], 1);
        }
    }
}

// ---------- scan stage A: per-block (1024 elems) totals ----------
__global__ void k_scanA(const int* __restrict__ cnt, int* __restrict__ parts, int n) {
    __shared__ int sm[4];
    int b = blockIdx.x, t = threadIdx.x;
    int idx = b * 256 + t;
    int i0 = idx * 4, s = 0;
    if (i0 + 3 < n) {
        int4 c = reinterpret_cast<const int4*>(cnt)[idx];
        s = c.x + c.y + c.z + c.w;
    } else {
        for (int k = i0; k < n; ++k) s += cnt[k];
    }
    s = wredi(s);
    int lane = t & 63, wv = t >> 6;
    if (lane == 0) sm[wv] = s;
    __syncthreads();
    if (t == 0) parts[b] = sm[0] + sm[1] + sm[2] + sm[3];
}

// ---------- scan stage C: base = sum(parts[<b]) via reduce; local scan; write row ----------
__global__ void k_scanC(const int* __restrict__ cnt, const int* __restrict__ parts,
                        int* __restrict__ row, int n) {
    __shared__ int smb[4], smw[4];
    int b = blockIdx.x, t = threadIdx.x;
    int lane = t & 63, wv = t >> 6;
    // base = sum of parts[0..b) (b < 256 blocks guaranteed by chunk=1024, n<=256K)
    int pv = (t < b) ? parts[t] : 0;
    pv = wredi(pv);
    if (lane == 0) smb[wv] = pv;
    // local: this thread's 4 counts
    int idx = b * 256 + t;
    int i0 = idx * 4;
    int c0 = 0, c1 = 0, c2 = 0, c3 = 0, s = 0;
    if (i0 + 3 < n) {
        int4 c = reinterpret_cast<const int4*>(cnt)[idx];
        c0 = c.x; c1 = c.y; c2 = c.z; c3 = c.w;
    } else {
        if (i0 + 0 < n) c0 = cnt[i0 + 0];
        if (i0 + 1 < n) c1 = cnt[i0 + 1];
        if (i0 + 2 < n) c2 = cnt[i0 + 2];
        if (i0 + 3 < n) c3 = cnt[i0 + 3];
    }
    s = c0 + c1 + c2 + c3;
    // inclusive wave scan of s
    int x = s;
    #pragma unroll
    for (int off = 1; off < 64; off <<= 1) {
        int y = __shfl_up(x, off, 64);
        if (lane >= off) x += y;
    }
    if (lane == 63) smw[wv] = x;
    __syncthreads();
    int base = smb[0] + smb[1] + smb[2] + smb[3];
    int wbase = 0;
    #pragma unroll
    for (int w = 0; w < 4; ++w) wbase += (w < wv) ? smw[w] : 0;
    int run = base + wbase + (x - s);   // exclusive prefix for this thread
    if (i0 + 0 < n) { row[i0 + 0] = run; run += c0; }
    if (i0 + 1 < n) { row[i0 + 1] = run; run += c1; }
    if (i0 + 2 < n) { row[i0 + 2] = run; run += c2; }
    if (i0 + 3 < n) { row[i0 + 3] = run; run += c3; }
}

// ---------- unified scatter (4 edges/thread); bumps row[d] in place ----------
// main: src(17b) | ftype(3b)<<17 | hour(3b)<<20 ; cat: csrc plain
__global__ void k_scatter(const int* __restrict__ src, const int* __restrict__ dst,
                          const int* __restrict__ ft, const int* __restrict__ hh,
                          const int* __restrict__ csrc, const int* __restrict__ cdst,
                          int* __restrict__ row, unsigned* __restrict__ recs,
                          int E, int EC, int N) {
    int tid = blockIdx.x * blockDim.x + threadIdx.x;
    int mainT = (E + 3) / 4;
    if (tid < mainT) {
        int i = tid * 4;
        if (i + 3 < E) {
            int4 s4 = reinterpret_cast<const int4*>(src)[tid];
            int4 d4 = reinterpret_cast<const int4*>(dst)[tid];
            int4 f4 = reinterpret_cast<const int4*>(ft)[tid];
            int4 h4 = reinterpret_cast<const int4*>(hh)[tid];
            int p;
            p = atomicAdd(&row[d4.x], 1);
            recs[p] = (unsigned)s4.x | ((unsigned)f4.x << 17) | ((unsigned)h4.x << 20);
            p = atomicAdd(&row[d4.y], 1);
            recs[p] = (unsigned)s4.y | ((unsigned)f4.y << 17) | ((unsigned)h4.y << 20);
            p = atomicAdd(&row[d4.z], 1);
            recs[p] = (unsigned)s4.z | ((unsigned)f4.z << 17) | ((unsigned)h4.z << 20);
            p = atomicAdd(&row[d4.w], 1);
            recs[p] = (unsigned)s4.w | ((unsigned)f4.w << 17) | ((unsigned)h4.w << 20);
        } else {
            for (int k = i; k < E; ++k) {
                int p = atomicAdd(&row[dst[k]], 1);
                recs[p] = (unsigned)src[k] | ((unsigned)ft[k] << 17) | ((unsigned)hh[k] << 20);
            }
        }
    } else {
        int j = (tid - mainT) * 4;
        if (j + 3 < EC) {
            int4 s4 = reinterpret_cast<const int4*>(csrc)[tid - mainT];
            int4 d4 = reinterpret_cast<const int4*>(cdst)[tid - mainT];
            int p;
            p = atomicAdd(&row[N + d4.x], 1); recs[p] = (unsigned)s4.x;
            p = atomicAdd(&row[N + d4.y], 1); recs[p] = (unsigned)s4.y;
            p = atomicAdd(&row[N + d4.z], 1); recs[p] = (unsigned)s4.z;
            p = atomicAdd(&row[N + d4.w], 1); recs[p] = (unsigned)s4.w;
        } else {
            for (int k = j; k < EC; ++k) {
                int p = atomicAdd(&row[N + cdst[k]], 1);
                recs[p] = (unsigned)csrc[k];
            }
        }
    }
}

// ---------- fused aggregation for BOTH graphs ----------
// After scatter, row[d] = segment END; start = row[d] - cnt[d].
// out[d] = sum_e es_e * h_e / sum_e es_e  (softmax denominator factors out).
__launch_bounds__(256)
__global__ void k_fused(const void* __restrict__ nfeat, const void* __restrict__ cemb,
                        const void* __restrict__ rel_emb, const void* __restrict__ norm_emb,
                        const float* __restrict__ trel,
                        const int* __restrict__ row, const int* __restrict__ cnt,
                        const unsigned* __restrict__ recs,
                        const int* __restrict__ flag, void* __restrict__ out,
                        int N, int M) {
    int f = *flag;
    __shared__ float srel[7 * D], snorm[7 * D], strel[HOUR_PERIOD * D];
    int tid = threadIdx.x;
    for (int i = tid; i < 7 * D; i += 256) srel[i] = ld1(rel_emb, i, f);
    for (int i = tid; i < 7 * D; i += 256) snorm[i] = ld1(norm_emb, i, f);
    for (int i = tid; i < HOUR_PERIOD * D; i += 256) strel[i] = trel[i];
    __syncthreads();
    int l = tid & 15;
    int d = blockIdx.x * 16 + (tid >> 4);
    if (d >= M) return;
    int i1 = row[d];
    int i0 = i1 - cnt[d];
    float a0 = 0.f, a1 = 0.f, a2 = 0.f, a3 = 0.f, se = 0.f;

    if (d < N) {
        // ---- main graph (TransH on relation + time hyperplanes) ----
        float4 tt = ld4(nfeat, d * 16 + l, f);
        float4 qv = *reinterpret_cast<float4*>(&snorm[5 * D + l * 4]);   // time_norm
        unsigned pkA = 0, pkB = 0;
        float4 hA = make_float4(0,0,0,0), hB = hA;
        if (i0 < i1)     { pkA = recs[i0];     hA = ld4(nfeat, (int)(pkA & 0x1FFFF) * 16 + l, f); }
        if (i0 + 1 < i1) { pkB = recs[i0 + 1]; hB = ld4(nfeat, (int)(pkB & 0x1FFFF) * 16 + l, f); }
        for (int i = i0; i < i1; ++i) {
            unsigned cpk = pkA; float4 ch = hA;
            pkA = pkB; hA = hB;
            if (i + 2 < i1) { pkB = recs[i + 2]; hB = ld4(nfeat, (int)(pkB & 0x1FFFF) * 16 + l, f); }
            int ft = (cpk >> 17) & 7, hh = (cpk >> 20) & 7;
            float4 nn4 = *reinterpret_cast<float4*>(&snorm[ft * D + l * 4]);
            float4 rr4 = *reinterpret_cast<float4*>(&srel[ft * D + l * 4]);
            float4 tr4 = *reinterpret_cast<float4*>(&strel[hh * D + l * 4]);
            float w0 = ch.x - tt.x, w1 = ch.y - tt.y, w2 = ch.z - tt.z, w3 = ch.w - tt.w;
            float al = qsum(w0*nn4.x + w1*nn4.y + w2*nn4.z + w3*nn4.w);  // (h-t).n
            float be = qsum(w0*qv.x + w1*qv.y + w2*qv.z + w3*qv.w);      // (h-t).q
            float u0 = w0 + rr4.x - al*nn4.x, u1 = w1 + rr4.y - al*nn4.y,
                  u2 = w2 + rr4.z - al*nn4.z, u3 = w3 + rr4.w - al*nn4.w;
            float v0 = w0 + tr4.x - be*qv.x, v1 = w1 + tr4.y - be*qv.y,
                  v2 = w2 + tr4.z - be*qv.z, v3 = w3 + tr4.w - be*qv.w;
            float ssq = qsum(u0*u0 + u1*u1 + u2*u2 + u3*u3 +
                             v0*v0 + v1*v1 + v2*v2 + v3*v3);
            float es = __expf(__expf(-ssq));   // exp(score*score_t), arg in (0,1]
            a0 += es * ch.x; a1 += es * ch.y; a2 += es * ch.z; a3 += es * ch.w;
            se += es;
        }
    } else {
        // ---- category graph (TransE) ----
        float4 tt = ld4(cemb, (d - N) * 16 + l, f);
        float4 r6 = *reinterpret_cast<float4*>(&srel[6 * D + l * 4]);
        float b0 = r6.x - tt.x, b1 = r6.y - tt.y, b2 = r6.z - tt.z, b3 = r6.w - tt.w;
        unsigned pkA = 0, pkB = 0;
        float4 hA = make_float4(0,0,0,0), hB = hA;
        if (i0 < i1)     { pkA = recs[i0];     hA = ld4(cemb, (int)pkA * 16 + l, f); }
        if (i0 + 1 < i1) { pkB = recs[i0 + 1]; hB = ld4(cemb, (int)pkB * 16 + l, f); }
        for (int i = i0; i < i1; ++i) {
            float4 ch = hA;
            pkA = pkB; hA = hB;
            if (i + 2 < i1) { pkB = recs[i + 2]; hB = ld4(cemb, (int)pkB * 16 + l, f); }
            float d0 = ch.x + b0, d1 = ch.y + b1, d2 = ch.z + b2, d3 = ch.w + b3;
            float ssq = qsum(d0*d0 + d1*d1 + d2*d2 + d3*d3);
            float es = __expf(__expf(-ssq));
            a0 += es * ch.x; a1 += es * ch.y; a2 += es * ch.z; a3 += es * ch.w;
            se += es;
        }
    }
    float inv = (se > 0.f) ? 1.f / se : 0.f;   // zero-degree row -> zeros
    int oi = d * 16 + l;
    if (f) {
        reinterpret_cast<float4*>(out)[oi] = make_float4(a0*inv, a1*inv, a2*inv, a3*inv);
    } else {
        ushort4 o;
        o.x = f2bf(a0*inv); o.y = f2bf(a1*inv); o.z = f2bf(a2*inv); o.w = f2bf(a3*inv);
        reinterpret_cast<ushort4*>(out)[oi] = o;
    }
}

extern "C" void kernel_launch(void* const* d_in, const int* in_sizes, int n_in,
                              void* d_out, int out_size, void* d_ws, size_t ws_size,
                              hipStream_t stream) {
    const void* nfeat    = d_in[0];
    const void* cemb     = d_in[1];
    const void* rel_emb  = d_in[2];
    const void* norm_emb = d_in[3];
    const void* hour_emb = d_in[4];
    const void* trw      = d_in[5];
    const void* trb      = d_in[6];
    const int* src    = (const int*)d_in[7];
    const int* dst    = (const int*)d_in[8];
    const int* ftype  = (const int*)d_in[9];
    const int* hourid = (const int*)d_in[10];
    const int* csrc   = (const int*)d_in[11];
    const int* cdst   = (const int*)d_in[12];

    const int N  = in_sizes[0] / D;
    const int NC = in_sizes[1] / D;
    const int E  = in_sizes[7];
    const int EC = in_sizes[11];
    const int M  = N + NC;          // unified dst space
    const int ET = E + EC;          // unified edge count

    // ---- ws layout (4B units): flag(16) trel(384) cnt(M) row(M) recs(ET) parts ----
    int* ws     = (int*)d_ws;
    int* flag   = ws;
    float* trel = (float*)(ws + 16);
    int* cnt    = ws + 16 + HOUR_PERIOD * D;
    int* row    = cnt + M;
    unsigned* recs = (unsigned*)(row + M);
    int* parts  = (int*)(recs + ET);

    int nparts = (M + 1023) / 1024;                 // 99 for M=100500 (< 256)
    int prepBlocks = ((M + 3) / 4 + 255) / 256;     // >= HOUR_PERIOD
    int histT = (E + 3) / 4 + (EC + 3) / 4;

    k_prep<<<prepBlocks, 256, 0, stream>>>(hour_emb, trw, trb, rel_emb,
                                           flag, trel, cnt, M);
    k_hist<<<(histT + 255) / 256, 256, 0, stream>>>(dst, cdst, cnt, E, EC, N);
    k_scanA<<<nparts, 256, 0, stream>>>(cnt, parts, M);
    k_scanC<<<nparts, 256, 0, stream>>>(cnt, parts, row, M);
    k_scatter<<<(histT + 255) / 256, 256, 0, stream>>>(src, dst, ftype, hourid,
                                                       csrc, cdst, row, recs, E, EC, N);
    k_fused<<<(M + 15) / 16, 256, 0, stream>>>(nfeat, cemb, rel_emb, norm_emb,
                                               trel, row, cnt, recs, flag,
                                               d_out, N, M);
}